// Round 1
// baseline (295.748 us; speedup 1.0000x reference)
//
#include <hip/hip_runtime.h>
#include <hip/hip_bf16.h>

#define U_ 2048
#define T_ 512
#define K_ 128
#define B_ 32
#define RHO_ 0.99f

__device__ __forceinline__ float fast_tanh(float x) {
  float e = __expf(2.0f * x);          // inf for large x -> returns +/-1 correctly
#if __has_builtin(__builtin_amdgcn_rcpf)
  return 1.0f - 2.0f * __builtin_amdgcn_rcpf(e + 1.0f);
#else
  return 1.0f - 2.0f / (e + 1.0f);
#endif
}

// u[m][n] = sum_k A[m][k] * W[k][n] + bias[n];  M=16384, K=128, N=2048
// 64x64 tile per 256-thread block, K processed in two 64-halves to keep LDS at
// 33.8 KB -> 4 blocks/CU.
__global__ __launch_bounds__(256, 4) void gemm_bias_kernel(
    const float* __restrict__ A, const float* __restrict__ W,
    const float* __restrict__ bias, float* __restrict__ out) {
  __shared__ float As[64][68];   // [k_local][m], +4 pad keeps rows 16B-aligned for b128
  __shared__ float Bs[64][64];   // [k_local][n]
  const int tid = threadIdx.x;
  const int m0 = blockIdx.y << 6;
  const int n0 = blockIdx.x << 6;

  const int tx = tid & 15;       // n quad index
  const int ty = tid >> 4;       // m quad index

  float acc[4][4] = {};

  #pragma unroll
  for (int kb = 0; kb < 2; ++kb) {
    if (kb) __syncthreads();
    // Stage A tile (64 rows x 64 k), transposed into As[k][m]
    {
      const int c4 = tid & 15;   // k-quad
      const int r0 = tid >> 4;   // row 0..15
      #pragma unroll
      for (int rr = 0; rr < 4; ++rr) {
        const int r = r0 + (rr << 4);
        const float4 v =
            *(const float4*)(A + (size_t)(m0 + r) * K_ + (kb << 6) + (c4 << 2));
        As[(c4 << 2) + 0][r] = v.x;
        As[(c4 << 2) + 1][r] = v.y;
        As[(c4 << 2) + 2][r] = v.z;
        As[(c4 << 2) + 3][r] = v.w;
      }
    }
    // Stage B tile (64 k x 64 n), natural layout
    {
      const int c4 = tid & 15;   // n-quad
      const int r0 = tid >> 4;   // k row 0..15
      #pragma unroll
      for (int rr = 0; rr < 4; ++rr) {
        const int k = r0 + (rr << 4);
        *(float4*)&Bs[k][c4 << 2] =
            *(const float4*)(W + (size_t)((kb << 6) + k) * U_ + n0 + (c4 << 2));
      }
    }
    __syncthreads();

    #pragma unroll 16
    for (int k = 0; k < 64; ++k) {
      const float4 a = *(const float4*)&As[k][ty << 2];
      const float4 b = *(const float4*)&Bs[k][tx << 2];
      acc[0][0] = fmaf(a.x, b.x, acc[0][0]);
      acc[0][1] = fmaf(a.x, b.y, acc[0][1]);
      acc[0][2] = fmaf(a.x, b.z, acc[0][2]);
      acc[0][3] = fmaf(a.x, b.w, acc[0][3]);
      acc[1][0] = fmaf(a.y, b.x, acc[1][0]);
      acc[1][1] = fmaf(a.y, b.y, acc[1][1]);
      acc[1][2] = fmaf(a.y, b.z, acc[1][2]);
      acc[1][3] = fmaf(a.y, b.w, acc[1][3]);
      acc[2][0] = fmaf(a.z, b.x, acc[2][0]);
      acc[2][1] = fmaf(a.z, b.y, acc[2][1]);
      acc[2][2] = fmaf(a.z, b.z, acc[2][2]);
      acc[2][3] = fmaf(a.z, b.w, acc[2][3]);
      acc[3][0] = fmaf(a.w, b.x, acc[3][0]);
      acc[3][1] = fmaf(a.w, b.y, acc[3][1]);
      acc[3][2] = fmaf(a.w, b.z, acc[3][2]);
      acc[3][3] = fmaf(a.w, b.w, acc[3][3]);
    }
  }

  const float4 bv = *(const float4*)(bias + n0 + (tx << 2));
  #pragma unroll
  for (int i = 0; i < 4; ++i) {
    float4 o;
    o.x = acc[i][0] + bv.x;
    o.y = acc[i][1] + bv.y;
    o.z = acc[i][2] + bv.z;
    o.w = acc[i][3] + bv.w;
    *(float4*)(out + (size_t)(m0 + (ty << 2) + i) * U_ + n0 + (tx << 2)) = o;
  }
}

// Diagonal-chain scan, in place on buf (which holds u + bias).
// Chain c of batch b computes h_t = tanh(w[t][(c+t)%U] + 0.99*h_{t-1}) and
// stores it at [t][(c+t)%U]. Each element belongs to exactly one chain.
__global__ __launch_bounds__(256) void ring_scan_kernel(
    float* __restrict__ buf, const float* __restrict__ h0) {
  const int b = blockIdx.y;
  const int c = (blockIdx.x << 8) + threadIdx.x;
  float* const base = buf + (size_t)b * (T_ * U_);
  float h = h0[((size_t)b << 11) + ((c + U_ - 1) & (U_ - 1))];

  float wA[8], wB[8];
  #pragma unroll
  for (int j = 0; j < 8; ++j)
    wA[j] = base[((size_t)j << 11) + ((c + j) & (U_ - 1))];

  for (int t0 = 0; t0 < T_; t0 += 16) {
    // prefetch group B: t0+8 .. t0+15 (t0 <= 496, so always in range)
    #pragma unroll
    for (int j = 0; j < 8; ++j) {
      const int t = t0 + 8 + j;
      wB[j] = base[((size_t)t << 11) + ((c + t) & (U_ - 1))];
    }
    // compute + store group A: t0 .. t0+7
    #pragma unroll
    for (int j = 0; j < 8; ++j) {
      const int t = t0 + j;
      h = fast_tanh(fmaf(RHO_, h, wA[j]));
      base[((size_t)t << 11) + ((c + t) & (U_ - 1))] = h;
    }
    // prefetch group A for next iteration: t0+16 .. t0+23
    if (t0 + 16 < T_) {
      #pragma unroll
      for (int j = 0; j < 8; ++j) {
        const int t = t0 + 16 + j;
        wA[j] = base[((size_t)t << 11) + ((c + t) & (U_ - 1))];
      }
    }
    // compute + store group B
    #pragma unroll
    for (int j = 0; j < 8; ++j) {
      const int t = t0 + 8 + j;
      h = fast_tanh(fmaf(RHO_, h, wB[j]));
      base[((size_t)t << 11) + ((c + t) & (U_ - 1))] = h;
    }
  }
}

extern "C" void kernel_launch(void* const* d_in, const int* in_sizes, int n_in,
                              void* d_out, int out_size, void* d_ws, size_t ws_size,
                              hipStream_t stream) {
  const float* A    = (const float*)d_in[0];   // inputs [B,T,D_IN]
  const float* h0   = (const float*)d_in[1];   // [B,U]
  const float* W    = (const float*)d_in[2];   // kernel [D_IN,U]
  const float* bias = (const float*)d_in[3];   // [U]
  float* out = (float*)d_out;                  // [B,T,U], used as u-scratch then h

  dim3 gemm_grid(U_ / 64, (B_ * T_) / 64);     // (32, 256)
  gemm_bias_kernel<<<gemm_grid, 256, 0, stream>>>(A, W, bias, out);

  dim3 scan_grid(U_ / 256, B_);                // (8, 32)
  ring_scan_kernel<<<scan_grid, 256, 0, stream>>>(out, h0);
}

// Round 3
// 294.999 us; speedup vs baseline: 1.0025x; 1.0025x over previous
//
#include <hip/hip_runtime.h>
#include <hip/hip_bf16.h>

#define U_ 2048
#define T_ 512
#define K_ 128
#define B_ 32
#define RHO_ 0.99f

typedef __attribute__((ext_vector_type(8))) short short8;
typedef __attribute__((ext_vector_type(4))) float f32x4;

__device__ __forceinline__ float fast_tanh(float x) {
  float e = __expf(2.0f * x);          // inf for large x -> returns +/-1 correctly
  return 1.0f - 2.0f / (e + 1.0f);
}

__device__ __forceinline__ unsigned short bf16_rne(float x) {
  unsigned int u = __float_as_uint(x);
  u += 0x7FFFu + ((u >> 16) & 1u);
  return (unsigned short)(u >> 16);
}

// ---------------- converts ----------------
// A [16384][128] fp32 -> Ab [16384][256] bf16 (k<128: hi, k>=128: lo residual)
// One thread per 4-element k-quad: 16384 rows * 32 quads = 524288 threads.
__global__ __launch_bounds__(256) void convert_a_kernel(
    const float* __restrict__ A, unsigned short* __restrict__ Ab) {
  const int gi = blockIdx.x * 256 + threadIdx.x;
  const int m = gi >> 5;          // 0..16383 (needs 2048 blocks!)
  const int kq = (gi & 31) << 2;
  const float4 v = *(const float4*)&A[(size_t)m * K_ + kq];
  ushort4 hi, lo;
  hi.x = bf16_rne(v.x); hi.y = bf16_rne(v.y); hi.z = bf16_rne(v.z); hi.w = bf16_rne(v.w);
  lo.x = bf16_rne(v.x - __uint_as_float((unsigned)hi.x << 16));
  lo.y = bf16_rne(v.y - __uint_as_float((unsigned)hi.y << 16));
  lo.z = bf16_rne(v.z - __uint_as_float((unsigned)hi.z << 16));
  lo.w = bf16_rne(v.w - __uint_as_float((unsigned)hi.w << 16));
  *(ushort4*)&Ab[(size_t)m * 256 + kq] = hi;
  *(ushort4*)&Ab[(size_t)m * 256 + 128 + kq] = lo;
}

// W [128][2048] fp32 -> Wbt [2048][256] bf16 transposed, duplicated along k
__global__ __launch_bounds__(256) void convert_w_kernel(
    const float* __restrict__ W, unsigned short* __restrict__ Wbt) {
  const int gi = blockIdx.x * 256 + threadIdx.x;   // 65536 threads
  const int kq = gi >> 11;        // 0..31
  const int n = gi & 2047;
  const int k = kq << 2;
  ushort4 w;
  w.x = bf16_rne(W[(size_t)(k + 0) * U_ + n]);
  w.y = bf16_rne(W[(size_t)(k + 1) * U_ + n]);
  w.z = bf16_rne(W[(size_t)(k + 2) * U_ + n]);
  w.w = bf16_rne(W[(size_t)(k + 3) * U_ + n]);
  *(ushort4*)&Wbt[(size_t)n * 256 + k] = w;
  *(ushort4*)&Wbt[(size_t)n * 256 + 128 + k] = w;
}

// ---------------- MFMA GEMM ----------------
// u_s[m][c] = sum_k Ab[m][k]*Wbt[n][k] + bias[n], written diagonally shifted:
// c = (n - t) & 2047, t = m & 511.  128x128 tile, 4 waves, 16x16x32 bf16 mfma.
#define SROW 72   // shorts per LDS row: 64 data + 8 pad (144 B, balanced b128 banks)

__global__ __launch_bounds__(256, 3) void mfma_gemm_kernel(
    const unsigned short* __restrict__ Ab, const unsigned short* __restrict__ Wbt,
    const float* __restrict__ bias, float* __restrict__ us) {
  __shared__ unsigned short As[128 * SROW];
  __shared__ unsigned short Bs[128 * SROW];
  const int tid = threadIdx.x;
  const int m0 = blockIdx.y << 7;
  const int n0 = blockIdx.x << 7;
  const int wave = tid >> 6;
  const int lane = tid & 63;
  const int r = lane & 15;        // row/col within 16x16 tile
  const int q = lane >> 4;        // quad
  const int mw = (wave >> 1) << 6;
  const int nw = (wave & 1) << 6;

  f32x4 acc[4][4] = {};

  const int c8 = tid & 7;         // 16B chunk within a 64-k row
  const int row0 = tid >> 3;      // 0..31

  #pragma unroll
  for (int s = 0; s < 4; ++s) {
    const int k0 = s << 6;
    if (s) __syncthreads();
    #pragma unroll
    for (int rr = 0; rr < 4; ++rr) {
      const int rl = row0 + (rr << 5);
      *(float4*)&As[rl * SROW + (c8 << 3)] =
          *(const float4*)&Ab[(size_t)(m0 + rl) * 256 + k0 + (c8 << 3)];
      *(float4*)&Bs[rl * SROW + (c8 << 3)] =
          *(const float4*)&Wbt[(size_t)(n0 + rl) * 256 + k0 + (c8 << 3)];
    }
    __syncthreads();
    #pragma unroll
    for (int kk = 0; kk < 2; ++kk) {
      short8 af[4], bf[4];
      #pragma unroll
      for (int i = 0; i < 4; ++i)
        af[i] = *(const short8*)&As[(mw + (i << 4) + r) * SROW + (kk << 5) + (q << 3)];
      #pragma unroll
      for (int j = 0; j < 4; ++j)
        bf[j] = *(const short8*)&Bs[(nw + (j << 4) + r) * SROW + (kk << 5) + (q << 3)];
      #pragma unroll
      for (int i = 0; i < 4; ++i)
        #pragma unroll
        for (int j = 0; j < 4; ++j)
          acc[i][j] = __builtin_amdgcn_mfma_f32_16x16x32_bf16(af[i], bf[j], acc[i][j], 0, 0, 0);
    }
  }

  // epilogue: +bias, shifted store  (D layout: col = lane&15, row = quad*4+reg)
  #pragma unroll
  for (int j = 0; j < 4; ++j) {
    const int n = n0 + nw + (j << 4) + r;
    const float bv = bias[n];
    #pragma unroll
    for (int i = 0; i < 4; ++i) {
      const int mb = m0 + mw + (i << 4) + (q << 2);
      #pragma unroll
      for (int reg = 0; reg < 4; ++reg) {
        const int m = mb + reg;
        const int t = m & (T_ - 1);
        us[((size_t)m << 11) + ((n - t) & (U_ - 1))] = acc[i][j][reg] + bv;
      }
    }
  }
}

// ---------------- scan (separate buffers, shifted reads) ----------------
__global__ __launch_bounds__(256) void ring_scan2_kernel(
    const float* __restrict__ us, const float* __restrict__ h0,
    float* __restrict__ out) {
  const int b = blockIdx.y;
  const int c = (blockIdx.x << 8) + threadIdx.x;
  const float* src = us + (size_t)b * (T_ * U_) + c;   // stride U_ per t
  float* const dst = out + (size_t)b * (T_ * U_);
  float h = h0[((size_t)b << 11) + ((c + U_ - 1) & (U_ - 1))];

  float w0[16], w1[16];
  #pragma unroll
  for (int j = 0; j < 16; ++j) w0[j] = src[(size_t)j << 11];

  for (int t0 = 0; t0 < T_; t0 += 32) {
    #pragma unroll
    for (int j = 0; j < 16; ++j)
      w1[j] = src[(size_t)(t0 + 16 + j) << 11];
    #pragma unroll
    for (int j = 0; j < 16; ++j) {
      const int t = t0 + j;
      h = fast_tanh(fmaf(RHO_, h, w0[j]));
      dst[((size_t)t << 11) + ((c + t) & (U_ - 1))] = h;
    }
    if (t0 + 32 < T_) {
      #pragma unroll
      for (int j = 0; j < 16; ++j)
        w0[j] = src[(size_t)(t0 + 32 + j) << 11];
    }
    #pragma unroll
    for (int j = 0; j < 16; ++j) {
      const int t = t0 + 16 + j;
      h = fast_tanh(fmaf(RHO_, h, w1[j]));
      dst[((size_t)t << 11) + ((c + t) & (U_ - 1))] = h;
    }
  }
}

// ---------------- fallback path (R1, proven correct) ----------------
__global__ __launch_bounds__(256, 4) void gemm_bias_kernel(
    const float* __restrict__ A, const float* __restrict__ W,
    const float* __restrict__ bias, float* __restrict__ out) {
  __shared__ float Asf[64][68];
  __shared__ float Bsf[64][64];
  const int tid = threadIdx.x;
  const int m0 = blockIdx.y << 6;
  const int n0 = blockIdx.x << 6;
  const int tx = tid & 15;
  const int ty = tid >> 4;
  float acc[4][4] = {};
  #pragma unroll
  for (int kb = 0; kb < 2; ++kb) {
    if (kb) __syncthreads();
    {
      const int c4 = tid & 15;
      const int r0 = tid >> 4;
      #pragma unroll
      for (int rr = 0; rr < 4; ++rr) {
        const int r = r0 + (rr << 4);
        const float4 v = *(const float4*)(A + (size_t)(m0 + r) * K_ + (kb << 6) + (c4 << 2));
        Asf[(c4 << 2) + 0][r] = v.x;
        Asf[(c4 << 2) + 1][r] = v.y;
        Asf[(c4 << 2) + 2][r] = v.z;
        Asf[(c4 << 2) + 3][r] = v.w;
      }
    }
    {
      const int c4 = tid & 15;
      const int r0 = tid >> 4;
      #pragma unroll
      for (int rr = 0; rr < 4; ++rr) {
        const int k = r0 + (rr << 4);
        *(float4*)&Bsf[k][c4 << 2] =
            *(const float4*)(W + (size_t)((kb << 6) + k) * U_ + n0 + (c4 << 2));
      }
    }
    __syncthreads();
    #pragma unroll 16
    for (int k = 0; k < 64; ++k) {
      const float4 a = *(const float4*)&Asf[k][ty << 2];
      const float4 b = *(const float4*)&Bsf[k][tx << 2];
      acc[0][0] = fmaf(a.x, b.x, acc[0][0]); acc[0][1] = fmaf(a.x, b.y, acc[0][1]);
      acc[0][2] = fmaf(a.x, b.z, acc[0][2]); acc[0][3] = fmaf(a.x, b.w, acc[0][3]);
      acc[1][0] = fmaf(a.y, b.x, acc[1][0]); acc[1][1] = fmaf(a.y, b.y, acc[1][1]);
      acc[1][2] = fmaf(a.y, b.z, acc[1][2]); acc[1][3] = fmaf(a.y, b.w, acc[1][3]);
      acc[2][0] = fmaf(a.z, b.x, acc[2][0]); acc[2][1] = fmaf(a.z, b.y, acc[2][1]);
      acc[2][2] = fmaf(a.z, b.z, acc[2][2]); acc[2][3] = fmaf(a.z, b.w, acc[2][3]);
      acc[3][0] = fmaf(a.w, b.x, acc[3][0]); acc[3][1] = fmaf(a.w, b.y, acc[3][1]);
      acc[3][2] = fmaf(a.w, b.z, acc[3][2]); acc[3][3] = fmaf(a.w, b.w, acc[3][3]);
    }
  }
  const float4 bv = *(const float4*)(bias + n0 + (tx << 2));
  #pragma unroll
  for (int i = 0; i < 4; ++i) {
    float4 o;
    o.x = acc[i][0] + bv.x; o.y = acc[i][1] + bv.y;
    o.z = acc[i][2] + bv.z; o.w = acc[i][3] + bv.w;
    *(float4*)(out + (size_t)(m0 + (ty << 2) + i) * U_ + n0 + (tx << 2)) = o;
  }
}

__global__ __launch_bounds__(256) void ring_scan_kernel(
    float* __restrict__ buf, const float* __restrict__ h0) {
  const int b = blockIdx.y;
  const int c = (blockIdx.x << 8) + threadIdx.x;
  float* const base = buf + (size_t)b * (T_ * U_);
  float h = h0[((size_t)b << 11) + ((c + U_ - 1) & (U_ - 1))];
  float wA[8], wB[8];
  #pragma unroll
  for (int j = 0; j < 8; ++j)
    wA[j] = base[((size_t)j << 11) + ((c + j) & (U_ - 1))];
  for (int t0 = 0; t0 < T_; t0 += 16) {
    #pragma unroll
    for (int j = 0; j < 8; ++j) {
      const int t = t0 + 8 + j;
      wB[j] = base[((size_t)t << 11) + ((c + t) & (U_ - 1))];
    }
    #pragma unroll
    for (int j = 0; j < 8; ++j) {
      const int t = t0 + j;
      h = fast_tanh(fmaf(RHO_, h, wA[j]));
      base[((size_t)t << 11) + ((c + t) & (U_ - 1))] = h;
    }
    if (t0 + 16 < T_) {
      #pragma unroll
      for (int j = 0; j < 8; ++j) {
        const int t = t0 + 16 + j;
        wA[j] = base[((size_t)t << 11) + ((c + t) & (U_ - 1))];
      }
    }
    #pragma unroll
    for (int j = 0; j < 8; ++j) {
      const int t = t0 + 8 + j;
      h = fast_tanh(fmaf(RHO_, h, wB[j]));
      base[((size_t)t << 11) + ((c + t) & (U_ - 1))] = h;
    }
  }
}

extern "C" void kernel_launch(void* const* d_in, const int* in_sizes, int n_in,
                              void* d_out, int out_size, void* d_ws, size_t ws_size,
                              hipStream_t stream) {
  const float* A    = (const float*)d_in[0];   // inputs [B,T,D_IN]
  const float* h0   = (const float*)d_in[1];   // [B,U]
  const float* W    = (const float*)d_in[2];   // kernel [D_IN,U]
  const float* bias = (const float*)d_in[3];   // [U]
  float* out = (float*)d_out;                  // [B,T,U]

  const size_t US_BYTES = (size_t)B_ * T_ * U_ * 4;          // 134,217,728
  const size_t AB_BYTES = (size_t)B_ * T_ * 256 * 2;         // 8,388,608
  const size_t WB_BYTES = (size_t)U_ * 256 * 2;              // 1,048,576
  const size_t NEEDED = US_BYTES + AB_BYTES + WB_BYTES;

  if (ws_size >= NEEDED) {
    float* us = (float*)d_ws;
    unsigned short* Ab  = (unsigned short*)((char*)d_ws + US_BYTES);
    unsigned short* Wbt = (unsigned short*)((char*)d_ws + US_BYTES + AB_BYTES);

    convert_a_kernel<<<2048, 256, 0, stream>>>(A, Ab);   // 16384 rows * 32 quads
    convert_w_kernel<<<256, 256, 0, stream>>>(W, Wbt);
    dim3 gg(U_ / 128, (B_ * T_) / 128);   // (16, 128)
    mfma_gemm_kernel<<<gg, 256, 0, stream>>>(Ab, Wbt, bias, us);
    dim3 sg(U_ / 256, B_);                // (8, 32)
    ring_scan2_kernel<<<sg, 256, 0, stream>>>(us, h0, out);
  } else {
    dim3 gemm_grid(U_ / 64, (B_ * T_) / 64);
    gemm_bias_kernel<<<gemm_grid, 256, 0, stream>>>(A, W, bias, out);
    dim3 scan_grid(U_ / 256, B_);
    ring_scan_kernel<<<scan_grid, 256, 0, stream>>>(out, h0);
  }
}